// Round 12
// baseline (391.541 us; speedup 1.0000x reference)
//
#include <hip/hip_runtime.h>
#include <cstdint>

#define BB 2048
#define TT 200
#define DD 128
#define H1 128
#define H2 64
#define MR (BB * TT)        // 409600 flat rows
#define NGRP (MR / 128)     // 3200 groups of 128 rows
#define GRID 256            // persistent blocks (1 per CU)
#define MASK_PAD -4294967295.0f

typedef __attribute__((ext_vector_type(8))) short short8;
typedef __attribute__((ext_vector_type(4))) float floatx4;

// ws layout (float offsets)
#define WS_WQAC   0          // fp32 [128][128]  Wqac[d][h] = W0a+W0c
#define WS_WCATT  16384      // bf16 [128][256]  WcatT[h][k]
#define WS_W1TB   32768      // bf16 [64][128]   W1^T
#define WS_QAS    36864      // fp32 [2048][128] qA
#define WS_LOGITS 299008     // fp32 [409600]    raw logits

static __device__ __forceinline__ unsigned short f2bf(float x) {
  union { float f; unsigned int u; } v; v.f = x;
  unsigned int r = v.u + 0x7FFF + ((v.u >> 16) & 1);  // RNE
  return (unsigned short)(r >> 16);
}

// ---------------------------------------------------------------------------
// Fold: Wqac (fp32), WcatT = [(W0b-W0c); W0d]^T (bf16 [128 h][256 k]),
//       W1tb = W1^T (bf16 [64 g][128 h]).
// ---------------------------------------------------------------------------
__global__ __launch_bounds__(256) void din_fold(
    const float* __restrict__ W0, const float* __restrict__ W1,
    float* __restrict__ ws) {
  int i = blockIdx.x * blockDim.x + threadIdx.x;
  if (i < 16384) {
    int d = i >> 7, h = i & 127;
    ws[WS_WQAC + i] = W0[d * 128 + h] + W0[(256 + d) * 128 + h];
  } else if (i < 49152) {
    int j = i - 16384;           // [h][k]
    int h = j >> 8, k = j & 255;
    float v;
    if (k < 128) v = W0[(128 + k) * 128 + h] - W0[(256 + k) * 128 + h];
    else         v = W0[(384 + (k - 128)) * 128 + h];
    ((unsigned short*)(ws + WS_WCATT))[j] = f2bf(v);
  } else if (i < 57344) {
    int j = i - 49152;           // [g][h]
    int g = j >> 7, h = j & 127;
    ((unsigned short*)(ws + WS_W1TB))[j] = f2bf(W1[h * 64 + g]);
  }
}

// ---------------------------------------------------------------------------
// QA: qas_g[b][h] = b0[h] + sum_d q[b][d] * Wqac[d][h]
// ---------------------------------------------------------------------------
__global__ __launch_bounds__(128) void din_qa(
    const float* __restrict__ query, const float* __restrict__ b0,
    const float* __restrict__ ws, float* __restrict__ qas_g) {
  const int b = blockIdx.x;
  const int h = threadIdx.x;
  __shared__ float qsh[DD];
  qsh[h] = query[(size_t)b * DD + h];
  __syncthreads();
  float acc = b0[h];
  const float* wq = ws + WS_WQAC + h;
  #pragma unroll 8
  for (int d = 0; d < DD; ++d) acc += qsh[d] * wq[d * 128];
  qas_g[(size_t)b * H1 + h] = acc;
}

// ---------------------------------------------------------------------------
// Logits: 256 persistent blocks x 512 threads (8 waves). Stage Wcat+W1 into
// swizzled LDS ONCE per block; then grid-stride 128-row groups. Each wave
// owns 16 rows end-to-end; zero barriers after staging; A2 wave-private.
// Key/q single-buffer prefetch (cvt -> issue-next -> compute).
// ---------------------------------------------------------------------------
__global__ __launch_bounds__(512, 2) void din_logits(
    const float* __restrict__ key, const float* __restrict__ query,
    const float* __restrict__ ws, const float* __restrict__ qas_g,
    const float* __restrict__ a0, const float* __restrict__ a1,
    const float* __restrict__ b1, const float* __restrict__ Wout,
    const float* __restrict__ bout, float* __restrict__ lgout) {
  const int tid = threadIdx.x;
  const int w = tid >> 6;        // 0..7
  const int l = tid & 63;
  const int lr = l & 15;
  const int kgrp = l >> 4;

  __shared__ unsigned short WC[128 * 256];    // 64 KB swizzled WcatT
  __shared__ unsigned short W1S[64 * 128];    // 16 KB swizzled W1T
  __shared__ unsigned short A2[8][16 * 128];  // 32 KB wave-private

  // ---- stage WC (4096 16B-chunks) and W1S (1024 chunks), swizzled ----
  {
    const unsigned short* wcsrc = (const unsigned short*)(ws + WS_WCATT);
    #pragma unroll
    for (int i = 0; i < 8; ++i) {
      int c = i * 512 + tid;               // chunk id
      int h = c >> 5, c8 = c & 31;         // 32 chunks per 512B row
      int4 v = *(const int4*)(wcsrc + c * 8);
      *(int4*)((char*)WC + h * 512 + ((c8 * 16) ^ ((h & 7) << 4))) = v;
    }
    const unsigned short* w1src = (const unsigned short*)(ws + WS_W1TB);
    #pragma unroll
    for (int i = 0; i < 2; ++i) {
      int c = i * 512 + tid;
      int g = c >> 4, c16 = c & 15;        // 16 chunks per 256B row
      int4 v = *(const int4*)(w1src + c * 8);
      *(int4*)((char*)W1S + g * 256 + ((c16 * 16) ^ ((g & 7) << 4))) = v;
    }
  }
  __syncthreads();   // ONLY barrier in this kernel

  char* a2b = (char*)A2[w];

  // per-lane constants
  float b1v[4], wov[4];
  #pragma unroll
  for (int nt = 0; nt < 4; ++nt) {
    int gc = nt * 16 + lr;
    b1v[nt] = b1[gc]; wov[nt] = Wout[gc];
  }
  const float bout0 = bout[0];

  // ---- prologue: issue first group's key/q loads ----
  float4 fk[8], fq[8];
  int g = blockIdx.x;
  {
    int gri = g * 128 + w * 16 + lr;
    int bi = gri / 200;
    const float* kr = key + (size_t)gri * DD + kgrp * 8;
    const float* qr = query + (size_t)bi * DD + kgrp * 8;
    #pragma unroll
    for (int ks = 0; ks < 4; ++ks) {
      fk[2 * ks]     = *(const float4*)(kr + ks * 32);
      fk[2 * ks + 1] = *(const float4*)(kr + ks * 32 + 4);
      fq[2 * ks]     = *(const float4*)(qr + ks * 32);
      fq[2 * ks + 1] = *(const float4*)(qr + ks * 32 + 4);
    }
  }

  // =============== persistent, barrier-free main loop ===============
  #pragma unroll 1
  while (g < NGRP) {
    const int grb = g * 128 + w * 16;

    // ---- cvt prefetched rows -> af[8] (k | q*k) ----
    short8 af[8];
    #pragma unroll
    for (int ks = 0; ks < 4; ++ks) {
      float4 k0 = fk[2 * ks], k1 = fk[2 * ks + 1];
      float4 q0 = fq[2 * ks], q1 = fq[2 * ks + 1];
      short8 ak, aq;
      ak[0] = (short)f2bf(k0.x); ak[1] = (short)f2bf(k0.y);
      ak[2] = (short)f2bf(k0.z); ak[3] = (short)f2bf(k0.w);
      ak[4] = (short)f2bf(k1.x); ak[5] = (short)f2bf(k1.y);
      ak[6] = (short)f2bf(k1.z); ak[7] = (short)f2bf(k1.w);
      aq[0] = (short)f2bf(q0.x * k0.x); aq[1] = (short)f2bf(q0.y * k0.y);
      aq[2] = (short)f2bf(q0.z * k0.z); aq[3] = (short)f2bf(q0.w * k0.w);
      aq[4] = (short)f2bf(q1.x * k1.x); aq[5] = (short)f2bf(q1.y * k1.y);
      aq[6] = (short)f2bf(q1.z * k1.z); aq[7] = (short)f2bf(q1.w * k1.w);
      af[ks] = ak; af[ks + 4] = aq;
    }

    // ---- issue NEXT group's loads into fk/fq (hidden under compute) ----
    {
      int gn = g + GRID;
      int gl = gn < NGRP ? gn : g;
      int gri = gl * 128 + w * 16 + lr;
      int bi = gri / 200;
      const float* kr = key + (size_t)gri * DD + kgrp * 8;
      const float* qr = query + (size_t)bi * DD + kgrp * 8;
      #pragma unroll
      for (int ks = 0; ks < 4; ++ks) {
        fk[2 * ks]     = *(const float4*)(kr + ks * 32);
        fk[2 * ks + 1] = *(const float4*)(kr + ks * 32 + 4);
        fq[2 * ks]     = *(const float4*)(qr + ks * 32);
        fq[2 * ks + 1] = *(const float4*)(qr + ks * 32 + 4);
      }
    }

    // ---- output row ids ----
    int bo[4], to[4];
    #pragma unroll
    for (int r = 0; r < 4; ++r) {
      int gro = grb + kgrp * 4 + r;
      bo[r] = gro / 200;
      to[r] = gro - bo[r] * 200;
    }

    // ---- GEMM1: 8 ksteps x 8 n-tiles, B from swizzled LDS ----
    floatx4 acc1[8];
    #pragma unroll
    for (int nt = 0; nt < 8; ++nt) acc1[nt] = (floatx4)(0.0f);
    #pragma unroll
    for (int ks = 0; ks < 8; ++ks) {
      #pragma unroll
      for (int nt = 0; nt < 8; ++nt) {
        int row = nt * 16 + lr;
        short8 bf = *(const short8*)((const char*)WC + row * 512 +
                                     ((ks * 64 + kgrp * 16) ^ ((row & 7) << 4)));
        acc1[nt] = __builtin_amdgcn_mfma_f32_16x16x32_bf16(af[ks], bf, acc1[nt], 0, 0, 0);
      }
    }

    // ---- epilogue 1: +qA, PReLU(a0), write H0 to wave-private LDS ----
    #pragma unroll
    for (int nt = 0; nt < 8; ++nt) {
      int h = nt * 16 + lr;
      #pragma unroll
      for (int r = 0; r < 4; ++r) {
        int t_loc = kgrp * 4 + r;
        float v = acc1[nt][r] + qas_g[(size_t)bo[r] * H1 + h];
        float a = a0[to[r] * H1 + h];
        v = v > 0.0f ? v : a * v;
        *(unsigned short*)(a2b + t_loc * 256 + ((h * 2) ^ ((t_loc & 7) << 4))) = f2bf(v);
      }
    }

    // ---- GEMM2: A from private LDS, B from swizzled LDS W1S ----
    short8 a2f[4];
    #pragma unroll
    for (int ks = 0; ks < 4; ++ks) {
      a2f[ks] = *(const short8*)(a2b + lr * 256 +
                                 ((ks * 64 + kgrp * 16) ^ ((lr & 7) << 4)));
    }
    floatx4 acc2[4];
    #pragma unroll
    for (int nt = 0; nt < 4; ++nt) acc2[nt] = (floatx4)(0.0f);
    #pragma unroll
    for (int ks = 0; ks < 4; ++ks) {
      #pragma unroll
      for (int nt = 0; nt < 4; ++nt) {
        int row = nt * 16 + lr;
        short8 bf = *(const short8*)((const char*)W1S + row * 256 +
                                     ((ks * 64 + kgrp * 16) ^ ((row & 7) << 4)));
        acc2[nt] = __builtin_amdgcn_mfma_f32_16x16x32_bf16(a2f[ks], bf, acc2[nt], 0, 0, 0);
      }
    }

    // ---- epilogue 2: +b1, PReLU(a1), *Wout, 16-lane reduce -> logits ----
    float p[4] = {0.f, 0.f, 0.f, 0.f};
    #pragma unroll
    for (int nt = 0; nt < 4; ++nt) {
      int gc = nt * 16 + lr;
      #pragma unroll
      for (int r = 0; r < 4; ++r) {
        float x = acc2[nt][r] + b1v[nt];
        float a = a1[to[r] * H2 + gc];
        x = x > 0.0f ? x : a * x;
        p[r] += x * wov[nt];
      }
    }
    #pragma unroll
    for (int m = 1; m < 16; m <<= 1) {
      #pragma unroll
      for (int r = 0; r < 4; ++r) p[r] += __shfl_xor(p[r], m);
    }
    if (lr == 0) {
      #pragma unroll
      for (int r = 0; r < 4; ++r) lgout[grb + kgrp * 4 + r] = bout0 + p[r];
    }
    g += GRID;
  }
}

// ---------------------------------------------------------------------------
// PV (+mask+softmax): out[b][d] = softmax(masked logits[b]) . val[b]
// ---------------------------------------------------------------------------
__global__ __launch_bounds__(256) void din_pv(
    const float* __restrict__ val, const int* __restrict__ mask,
    const float* __restrict__ logits, float* __restrict__ out) {
  const int b = blockIdx.x;
  const int tid = threadIdx.x;
  const int w = tid >> 6;
  const int l = tid & 63;
  __shared__ float eL[TT];
  __shared__ float red4[8];
  __shared__ float red[8 * DD];

  float lv = -INFINITY;
  if (tid < TT) {
    float lg = logits[(size_t)b * TT + tid];
    int mk = mask[(size_t)b * TT + tid];
    lv = (mk == 0) ? MASK_PAD : lg;
  }
  {
    float m = lv;
    #pragma unroll
    for (int off = 32; off >= 1; off >>= 1) m = fmaxf(m, __shfl_xor(m, off));
    if (l == 0) red4[w] = m;
  }
  __syncthreads();
  float mx = fmaxf(fmaxf(red4[0], red4[1]), fmaxf(red4[2], red4[3]));
  float e = (tid < TT) ? __expf(lv - mx) : 0.0f;
  {
    float s = e;
    #pragma unroll
    for (int off = 32; off >= 1; off >>= 1) s += __shfl_xor(s, off);
    if (l == 0) red4[4 + w] = s;
  }
  __syncthreads();
  float inv = 1.0f / (red4[4] + red4[5] + red4[6] + red4[7]);
  if (tid < TT) eL[tid] = e * inv;
  __syncthreads();

  const int group = tid >> 5;
  const int d4 = (tid & 31) * 4;
  const float* vb = val + (size_t)b * TT * DD;
  float4 acc4 = make_float4(0.f, 0.f, 0.f, 0.f);
  #pragma unroll 5
  for (int t = group * 25; t < group * 25 + 25; ++t) {
    float4 v = *(const float4*)(vb + (size_t)t * DD + d4);
    float wt = eL[t];
    acc4.x += wt * v.x; acc4.y += wt * v.y;
    acc4.z += wt * v.z; acc4.w += wt * v.w;
  }
  *(float4*)&red[group * DD + d4] = acc4;
  __syncthreads();
  if (tid < DD) {
    float s = 0.0f;
    #pragma unroll
    for (int gg = 0; gg < 8; ++gg) s += red[gg * DD + tid];
    out[(size_t)b * DD + tid] = s;
  }
}

extern "C" void kernel_launch(void* const* d_in, const int* in_sizes, int n_in,
                              void* d_out, int out_size, void* d_ws, size_t ws_size,
                              hipStream_t stream) {
  const float* query = (const float*)d_in[0];
  const float* key   = (const float*)d_in[1];
  const float* val   = (const float*)d_in[2];
  const int*   mask  = (const int*)d_in[3];
  const float* W0    = (const float*)d_in[4];
  const float* b0    = (const float*)d_in[5];
  const float* a0    = (const float*)d_in[6];
  const float* W1    = (const float*)d_in[7];
  const float* b1    = (const float*)d_in[8];
  const float* a1    = (const float*)d_in[9];
  const float* Wout  = (const float*)d_in[10];
  const float* bout  = (const float*)d_in[11];
  float* out = (float*)d_out;
  float* ws  = (float*)d_ws;
  float* qas_g  = ws + WS_QAS;
  float* logits = ws + WS_LOGITS;

  hipLaunchKernelGGL(din_fold, dim3(224), dim3(256), 0, stream, W0, W1, ws);
  hipLaunchKernelGGL(din_qa, dim3(BB), dim3(128), 0, stream, query, b0, ws, qas_g);
  hipLaunchKernelGGL(din_logits, dim3(GRID), dim3(512), 0, stream,
                     key, query, ws, qas_g, a0, a1, b1, Wout, bout, logits);
  hipLaunchKernelGGL(din_pv, dim3(BB), dim3(256), 0, stream, val, mask, logits, out);
}

// Round 13
// 198.328 us; speedup vs baseline: 1.9742x; 1.9742x over previous
//
#include <hip/hip_runtime.h>
#include <cstdint>

#define BB 2048
#define TT 200
#define DD 128
#define H1 128
#define H2 64
#define MASK_PAD -4294967295.0f

typedef __attribute__((ext_vector_type(8))) short short8;
typedef __attribute__((ext_vector_type(4))) float floatx4;

#define ATTN_OFF 57344  // float offset of attn[2048][200] in ws

static __device__ __forceinline__ unsigned short f2bf(float x) {
  union { float f; unsigned int u; } v; v.f = x;
  unsigned int r = v.u + 0x7FFF + ((v.u >> 16) & 1);  // RNE
  return (unsigned short)(r >> 16);
}

// ---------------------------------------------------------------------------
// Fold kernel -> ws:
//   Wqac[d][h] = W0a[d][h] + W0c[d][h]          fp32 [128][128] @ float 0
//   WkT [h][d] = (W0b - W0c)[d][h]              fp32 [128][128] @ float 16384
//   WdT [h][d] = W0d[d][h]                      fp32 [128][128] @ float 32768
//   W1tb[g][h] = bf16(W1[h][g])                 bf16 [64][128]  @ float 49152
// ---------------------------------------------------------------------------
__global__ void din_fold(const float* __restrict__ W0,
                         const float* __restrict__ W1,
                         float* __restrict__ ws) {
  int i = blockIdx.x * blockDim.x + threadIdx.x;
  if (i < 16384) {
    int d = i >> 7, h = i & 127;
    ws[i] = W0[d * 128 + h] + W0[(256 + d) * 128 + h];
  } else if (i < 32768) {
    int j = i - 16384; int h = j >> 7, d = j & 127;
    ws[16384 + j] = W0[(128 + d) * 128 + h] - W0[(256 + d) * 128 + h];
  } else if (i < 49152) {
    int j = i - 32768; int h = j >> 7, d = j & 127;
    ws[32768 + j] = W0[(384 + d) * 128 + h];
  } else if (i < 57344) {
    int j = i - 49152; int g = j >> 7, h = j & 127;
    ((unsigned short*)(ws + 49152))[j] = f2bf(W1[h * 64 + g]);
  }
}

// ---------------------------------------------------------------------------
// Kernel A: logits + softmax -> attn. One block per b, 4 independent waves.
// R6 structure: Wb = bf16(WkT + q_d*WdT) staged in LDS (swizzled), W1s in
// LDS, per-wave-private A2 transpose buffers, barrier-free main loop with
// next-tile key prefetch and pre-GEMM a0/a1 prefetch.
// ONLY change vs R6: __launch_bounds__(256, 1) -> VGPR cap 512, no spill.
// (LDS 67.6 KB caps us at 2 blocks/CU regardless, so no occupancy loss.)
// ---------------------------------------------------------------------------
__global__ __launch_bounds__(256, 1) void din_logits(
    const float* __restrict__ query, const float* __restrict__ key,
    const int* __restrict__ mask,
    const float* __restrict__ b0, const float* __restrict__ a0,
    const float* __restrict__ b1, const float* __restrict__ a1,
    const float* __restrict__ Wout, const float* __restrict__ bout,
    const float* __restrict__ ws, float* __restrict__ attn_out) {
  const int b = blockIdx.x;
  const int tid = threadIdx.x;
  const int w = tid >> 6;
  const int l = tid & 63;

  __shared__ unsigned short Wb[128 * 128];    // 32 KB folded W_b bf16 (swz)
  __shared__ unsigned short W1s[64 * 128];    // 16 KB W1^T bf16 (swz)
  __shared__ unsigned short A2[4][16 * 128];  // 16 KB per-wave H0 (swz)
  __shared__ float qs[DD];
  __shared__ float qas[H1];
  __shared__ float logitsAll[208];
  __shared__ float red4[8];

  const float* Wqac = ws;
  const float* WkT  = ws + 16384;
  const float* WdT  = ws + 32768;
  const unsigned short* W1tb = (const unsigned short*)(ws + 49152);

  // ---- stage q ----
  if (tid < DD) qs[tid] = query[(size_t)b * DD + tid];
  __syncthreads();

  // ---- build Wb = bf16(WkT[h][d] + q[d]*WdT[h][d]), swizzled ----
  #pragma unroll
  for (int j = 0; j < 16; ++j) {
    int flat = j * 1024 + tid * 4;
    int h = flat >> 7, d = flat & 127;
    float4 kv = *(const float4*)(WkT + flat);
    float4 dv = *(const float4*)(WdT + flat);
    ushort4 u;
    u.x = f2bf(kv.x + qs[d] * dv.x);
    u.y = f2bf(kv.y + qs[d + 1] * dv.y);
    u.z = f2bf(kv.z + qs[d + 2] * dv.z);
    u.w = f2bf(kv.w + qs[d + 3] * dv.w);
    *(ushort4*)((char*)Wb + h * 256 + ((d * 2) ^ ((h & 7) << 4))) = u;
  }
  // ---- copy W1s (swizzled) ----
  #pragma unroll
  for (int j = 0; j < 8; ++j) {
    int flat = j * 1024 + tid * 4;
    int g = flat >> 7, h = flat & 127;
    ushort4 u = *(const ushort4*)(W1tb + flat);
    *(ushort4*)((char*)W1s + g * 256 + ((h * 2) ^ ((g & 7) << 4))) = u;
  }
  // ---- qA ----
  if (tid < H1) {
    float acc = b0[tid];
    const float* wq = Wqac + tid;
    #pragma unroll 8
    for (int d = 0; d < DD; ++d) acc += qs[d] * wq[d * 128];
    qas[tid] = acc;
  }
  __syncthreads();  // Wb, W1s, qas ready — last barrier before softmax

  const int kgrp = l >> 4;            // 0..3
  const int lr = l & 15;
  char* a2b = (char*)A2[w];

  // per-lane epilogue-2 constants (g-cols this lane owns)
  float b1v[4], wov[4];
  #pragma unroll
  for (int nt = 0; nt < 4; ++nt) {
    int g = nt * 16 + lr;
    b1v[nt] = b1[g]; wov[nt] = Wout[g];
  }
  const float bout0 = bout[0];

  // ---- prologue: prefetch first tile's key chunk ----
  float4 fa[8];
  int mt = w;
  {
    int trow = mt * 16 + lr; if (trow > 199) trow = 199;
    const float* ar = key + ((size_t)b * TT + trow) * DD + kgrp * 8;
    #pragma unroll
    for (int ks = 0; ks < 4; ++ks) {
      fa[2 * ks]     = *(const float4*)(ar + ks * 32);
      fa[2 * ks + 1] = *(const float4*)(ar + ks * 32 + 4);
    }
  }

  // =============== barrier-free per-wave M-tile loop ===============
  #pragma unroll 1
  while (mt < 13) {
    // ---- convert prefetched key to bf16 A-frags ----
    short8 af[4];
    #pragma unroll
    for (int ks = 0; ks < 4; ++ks) {
      float4 f0 = fa[2 * ks], f1 = fa[2 * ks + 1];
      short8 t;
      t[0] = (short)f2bf(f0.x); t[1] = (short)f2bf(f0.y);
      t[2] = (short)f2bf(f0.z); t[3] = (short)f2bf(f0.w);
      t[4] = (short)f2bf(f1.x); t[5] = (short)f2bf(f1.y);
      t[6] = (short)f2bf(f1.z); t[7] = (short)f2bf(f1.w);
      af[ks] = t;
    }
    // ---- prefetch NEXT tile's key (hidden under this tile's compute) ----
    int mtn = mt + 4;
    if (mtn < 13) {
      int trow = mtn * 16 + lr; if (trow > 199) trow = 199;
      const float* ar = key + ((size_t)b * TT + trow) * DD + kgrp * 8;
      #pragma unroll
      for (int ks = 0; ks < 4; ++ks) {
        fa[2 * ks]     = *(const float4*)(ar + ks * 32);
        fa[2 * ks + 1] = *(const float4*)(ar + ks * 32 + 4);
      }
    }
    // ---- issue a0/a1 loads for THIS tile (hide under GEMM1) ----
    float a0v[8][4], a1v[4][4];
    #pragma unroll
    for (int r = 0; r < 4; ++r) {
      int tg = mt * 16 + kgrp * 4 + r; if (tg > 199) tg = 199;
      #pragma unroll
      for (int nt = 0; nt < 8; ++nt)
        a0v[nt][r] = a0[tg * H1 + nt * 16 + lr];
      #pragma unroll
      for (int nt = 0; nt < 4; ++nt)
        a1v[nt][r] = a1[tg * H2 + nt * 16 + lr];
    }

    // ---- GEMM1: full width (8 n-tiles), B from LDS ----
    floatx4 acc1[8];
    #pragma unroll
    for (int nt = 0; nt < 8; ++nt) acc1[nt] = (floatx4)(0.0f);
    #pragma unroll
    for (int ks = 0; ks < 4; ++ks) {
      #pragma unroll
      for (int nt = 0; nt < 8; ++nt) {
        int h = nt * 16 + lr;
        short8 bf = *(const short8*)((const char*)Wb + h * 256 +
                                     ((ks * 64 + kgrp * 16) ^ ((h & 7) << 4)));
        acc1[nt] = __builtin_amdgcn_mfma_f32_16x16x32_bf16(af[ks], bf, acc1[nt], 0, 0, 0);
      }
    }
    // ---- epilogue 1: +qA, PReLU(a0), write H0 to private LDS (swz) ----
    #pragma unroll
    for (int nt = 0; nt < 8; ++nt) {
      int h = nt * 16 + lr;
      float qa = qas[h];
      #pragma unroll
      for (int r = 0; r < 4; ++r) {
        int t_loc = kgrp * 4 + r;
        float v = acc1[nt][r] + qa;
        float a = a0v[nt][r];
        v = v > 0.0f ? v : a * v;
        *(unsigned short*)(a2b + t_loc * 256 + ((h * 2) ^ ((t_loc & 7) << 4))) = f2bf(v);
      }
    }
    // ---- GEMM2: A from private LDS, B from LDS W1s ----
    short8 a2f[4];
    #pragma unroll
    for (int ks = 0; ks < 4; ++ks) {
      a2f[ks] = *(const short8*)(a2b + lr * 256 +
                                 ((ks * 64 + kgrp * 16) ^ ((lr & 7) << 4)));
    }
    floatx4 acc2[4];
    #pragma unroll
    for (int nt = 0; nt < 4; ++nt) acc2[nt] = (floatx4)(0.0f);
    #pragma unroll
    for (int ks = 0; ks < 4; ++ks) {
      #pragma unroll
      for (int nt = 0; nt < 4; ++nt) {
        int g = nt * 16 + lr;
        short8 bf = *(const short8*)((const char*)W1s + g * 256 +
                                     ((ks * 64 + kgrp * 16) ^ ((g & 7) << 4)));
        acc2[nt] = __builtin_amdgcn_mfma_f32_16x16x32_bf16(a2f[ks], bf, acc2[nt], 0, 0, 0);
      }
    }
    // ---- epilogue 2: +b1, PReLU(a1), *Wout, 16-lane reduce -> logits ----
    float p[4] = {0.f, 0.f, 0.f, 0.f};
    #pragma unroll
    for (int nt = 0; nt < 4; ++nt) {
      #pragma unroll
      for (int r = 0; r < 4; ++r) {
        float x = acc2[nt][r] + b1v[nt];
        float a = a1v[nt][r];
        x = x > 0.0f ? x : a * x;
        p[r] += x * wov[nt];
      }
    }
    #pragma unroll
    for (int m = 1; m < 16; m <<= 1) {
      #pragma unroll
      for (int r = 0; r < 4; ++r) p[r] += __shfl_xor(p[r], m);
    }
    if (lr == 0) {
      #pragma unroll
      for (int r = 0; r < 4; ++r) {
        int tg = mt * 16 + kgrp * 4 + r;
        if (tg < TT) {
          int mk = mask[(size_t)b * TT + tg];
          logitsAll[tg] = (mk == 0) ? MASK_PAD : (bout0 + p[r]);
        }
      }
    }
    mt = mtn;
  }
  __syncthreads();

  // =================== softmax -> normalized attn ===================
  float lv = (tid < TT) ? logitsAll[tid] : -INFINITY;
  {
    float m = lv;
    #pragma unroll
    for (int off = 32; off >= 1; off >>= 1) m = fmaxf(m, __shfl_xor(m, off));
    if (l == 0) red4[w] = m;
  }
  __syncthreads();
  float mx = fmaxf(fmaxf(red4[0], red4[1]), fmaxf(red4[2], red4[3]));
  float e = (tid < TT) ? __expf(lv - mx) : 0.0f;
  {
    float s = e;
    #pragma unroll
    for (int off = 32; off >= 1; off >>= 1) s += __shfl_xor(s, off);
    if (l == 0) red4[4 + w] = s;
  }
  __syncthreads();
  float denom = red4[4] + red4[5] + red4[6] + red4[7];
  float inv = 1.0f / denom;
  if (tid < TT) attn_out[(size_t)b * TT + tid] = e * inv;
}

// ---------------------------------------------------------------------------
// Kernel B: PV. out[b][d] = sum_t attn[b][t] * val[b][t][d].
// ---------------------------------------------------------------------------
__global__ __launch_bounds__(256) void din_pv(
    const float* __restrict__ val, const float* __restrict__ attn,
    float* __restrict__ out) {
  const int b = blockIdx.x;
  const int tid = threadIdx.x;
  __shared__ float eL[TT];
  __shared__ float red[8 * DD];

  if (tid < TT) eL[tid] = attn[(size_t)b * TT + tid];
  __syncthreads();

  const int group = tid >> 5;
  const int d4 = (tid & 31) * 4;
  const float* vb = val + (size_t)b * TT * DD;
  float4 acc4 = make_float4(0.f, 0.f, 0.f, 0.f);
  #pragma unroll 5
  for (int t = group * 25; t < group * 25 + 25; ++t) {
    float4 v = *(const float4*)(vb + (size_t)t * DD + d4);
    float wt = eL[t];
    acc4.x += wt * v.x; acc4.y += wt * v.y;
    acc4.z += wt * v.z; acc4.w += wt * v.w;
  }
  *(float4*)&red[group * DD + d4] = acc4;
  __syncthreads();
  if (tid < DD) {
    float s = 0.0f;
    #pragma unroll
    for (int g = 0; g < 8; ++g) s += red[g * DD + tid];
    out[(size_t)b * DD + tid] = s;
  }
}

extern "C" void kernel_launch(void* const* d_in, const int* in_sizes, int n_in,
                              void* d_out, int out_size, void* d_ws, size_t ws_size,
                              hipStream_t stream) {
  const float* query = (const float*)d_in[0];
  const float* key   = (const float*)d_in[1];
  const float* val   = (const float*)d_in[2];
  const int*   mask  = (const int*)d_in[3];
  const float* W0    = (const float*)d_in[4];
  const float* b0    = (const float*)d_in[5];
  const float* a0    = (const float*)d_in[6];
  const float* W1    = (const float*)d_in[7];
  const float* b1    = (const float*)d_in[8];
  const float* a1    = (const float*)d_in[9];
  const float* Wout  = (const float*)d_in[10];
  const float* bout  = (const float*)d_in[11];
  float* out = (float*)d_out;
  float* ws  = (float*)d_ws;
  float* attn = ws + ATTN_OFF;

  hipLaunchKernelGGL(din_fold, dim3(224), dim3(256), 0, stream, W0, W1, ws);
  hipLaunchKernelGGL(din_logits, dim3(BB), dim3(256), 0, stream,
                     query, key, mask, b0, a0, b1, a1, Wout, bout, ws, attn);
  hipLaunchKernelGGL(din_pv, dim3(BB), dim3(256), 0, stream, val, attn, out);
}